// Round 5
// baseline (1220.362 us; speedup 1.0000x reference)
//
#include <hip/hip_runtime.h>

// Bilinear resampling: feature_map [C,H,W] fp32, target_uv [N,2] fp32, downscale (int scalar)
// out [C,N] fp32.
//
// Strategy (R5): TCP-gather cost model says time ~ scattered lane-dwords (1.8cy each).
// So: spatially bin points (32x32 px), stage each bin's 33x33 map region in LDS,
// gather from LDS (cheap), scatter-store the output (4x fewer scattered dwords).
constexpr int C = 128, H = 376, W = 1248;
constexpr int HW = H * W;

constexpr int BIN  = 32;                 // bin edge in pixels
constexpr int BU   = (W + BIN - 1) / BIN;   // 39
constexpr int BV   = (H + BIN - 1) / BIN;   // 12
constexpr int NBINS = BU * BV;              // 468
constexpr int CPG  = 8;                  // channels per block
constexpr int NCG  = C / CPG;            // 16
constexpr int RW   = BIN + 1;            // 33 region cols
constexpr int RH   = BIN + 1;            // 33 region rows
constexpr int RS   = RW + 1;             // 34 LDS row stride (pad)
constexpr int CH_STRIDE = RH * RS;       // 1122 floats per channel region

// d_ws layout (16B aligned chunks)
constexpr size_t WS_HIST   = 0;          // int[NBINS]
constexpr size_t WS_CURSOR = 4096;       // int[NBINS]
constexpr size_t WS_STARTS = 8192;       // int[NBINS+1]
constexpr size_t WS_SORTED = 16384;      // uint4[N]

__global__ __launch_bounds__(512) void k0_zero(int* hist, int* cursor) {
    for (int i = threadIdx.x; i < NBINS; i += 512) { hist[i] = 0; cursor[i] = 0; }
}

__global__ __launch_bounds__(256) void k1_count(const float* __restrict__ uv,
                                                const int* __restrict__ dsp,
                                                int* __restrict__ hist, int N) {
    int n = blockIdx.x * 256 + threadIdx.x;
    if (n >= N) return;
    float dsf = (float)dsp[0];
    float2 p = ((const float2*)uv)[n];
    int ul = (int)(p.x / dsf);
    int vl = (int)(p.y / dsf);
    int bin = (vl >> 5) * BU + (ul >> 5);
    atomicAdd(hist + bin, 1);
}

__global__ __launch_bounds__(512) void k2_scan(const int* __restrict__ hist,
                                               int* __restrict__ starts,
                                               int* __restrict__ cursor) {
    __shared__ int sh[512];
    int t = threadIdx.x;
    sh[t] = (t < NBINS) ? hist[t] : 0;
    __syncthreads();
    // Hillis-Steele inclusive scan
    for (int off = 1; off < 512; off <<= 1) {
        int v = (t >= off) ? sh[t - off] : 0;
        __syncthreads();
        sh[t] += v;
        __syncthreads();
    }
    if (t < NBINS) {
        starts[t + 1] = sh[t];
        int excl = sh[t] - hist[t];
        cursor[t] = excl;
        if (t == 0) starts[0] = 0;
    }
}

__global__ __launch_bounds__(256) void k3_scatter(const float* __restrict__ uv,
                                                  const int* __restrict__ dsp,
                                                  int* __restrict__ cursor,
                                                  uint4* __restrict__ sorted, int N) {
    int n = blockIdx.x * 256 + threadIdx.x;
    if (n >= N) return;
    float dsf = (float)dsp[0];
    float2 p = ((const float2*)uv)[n];
    float u = p.x / dsf, v = p.y / dsf;
    int ul = (int)u, vl = (int)v;
    float du = u - (float)ul, dv = v - (float)vl;
    int bin = (vl >> 5) * BU + (ul >> 5);
    int pos = atomicAdd(cursor + bin, 1);
    uint4 rec;
    rec.x = (unsigned)(ul | (vl << 16));
    rec.y = __float_as_uint(du);
    rec.z = __float_as_uint(dv);
    rec.w = (unsigned)n;
    sorted[pos] = rec;
}

__global__ __launch_bounds__(256) void k4_resample(const float* __restrict__ fmap,
                                                   const uint4* __restrict__ sorted,
                                                   const int* __restrict__ starts,
                                                   float* __restrict__ out, int N) {
    __shared__ float lds[CPG * CH_STRIDE];   // 35,904 B

    int bin = blockIdx.x >> 4;      // / NCG
    int cg  = blockIdx.x & 15;      // % NCG
    int bu  = bin % BU;
    int bv  = bin / BU;
    int u0  = bu * BIN;
    int v0  = bv * BIN;
    int cb  = cg * CPG;
    int tid = threadIdx.x;

    // Stage 33x33 region of CPG channels into LDS, coalesced, bounds-clamped.
#pragma unroll
    for (int c = 0; c < CPG; ++c) {
        const float* src = fmap + (size_t)(cb + c) * HW;
        for (int idx = tid; idx < RH * RW; idx += 256) {
            int r  = idx / RW;
            int cc = idx - r * RW;
            int gr = min(v0 + r, H - 1);
            int gc = min(u0 + cc, W - 1);
            lds[c * CH_STRIDE + r * RS + cc] = src[(size_t)gr * W + gc];
        }
    }
    __syncthreads();

    int s = starts[bin], e = starts[bin + 1];
    for (int p = s + tid; p < e; p += 256) {
        uint4 pt = sorted[p];
        int ul = (int)(pt.x & 0xffffu);
        int vl = (int)(pt.x >> 16);
        float du = __uint_as_float(pt.y);
        float dv = __uint_as_float(pt.z);
        int n = (int)pt.w;

        float w00 = (1.0f - dv) * (1.0f - du);
        float w10 = dv * (1.0f - du);
        float w01 = (1.0f - dv) * du;
        float w11 = dv * du;

        const float* base = &lds[(vl - v0) * RS + (ul - u0)];
        float* op = out + (size_t)cb * N + n;
#pragma unroll
        for (int c = 0; c < CPG; ++c) {
            float f00 = base[c * CH_STRIDE];
            float f01 = base[c * CH_STRIDE + 1];
            float f10 = base[c * CH_STRIDE + RS];
            float f11 = base[c * CH_STRIDE + RS + 1];
            float r = f00 * w00 + f10 * w10 + f01 * w01 + f11 * w11;
            __builtin_nontemporal_store(r, op);
            op += N;
        }
    }
}

// ---- Fallback (R2 structure) if ws too small ----
constexpr int F_CPG = 2;
constexpr int F_CG  = C / F_CPG;
constexpr int F_GPX = F_CG / 8;

__global__ __launch_bounds__(256) void fallback_kernel(
    const float* __restrict__ fmap, const float* __restrict__ uv,
    const int* __restrict__ dsp, float* __restrict__ out, int N, int NBX)
{
    int bid = blockIdx.x;
    int xcd = bid & 7;
    int j   = bid >> 3;
    int g_local = j / NBX;
    int nb      = j - g_local * NBX;
    int g   = xcd * F_GPX + g_local;

    int n = nb * 256 + threadIdx.x;
    if (n >= N) return;

    float dsf = (float)dsp[0];
    float2 p = ((const float2*)uv)[n];
    float u = p.x / dsf, v = p.y / dsf;
    int u_lo = (int)u, v_lo = (int)v;
    float du = u - (float)u_lo, dv = v - (float)v_lo;

    float w00 = (1.0f - dv) * (1.0f - du);
    float w10 = dv * (1.0f - du);
    float w01 = (1.0f - dv) * du;
    float w11 = dv * du;

    int cbase = g * F_CPG;
    const float* fp = fmap + (size_t)cbase * HW + (size_t)v_lo * W + u_lo;
    float*       op = out  + (size_t)cbase * N + n;
#pragma unroll
    for (int c = 0; c < F_CPG; ++c) {
        float f00 = fp[0], f01 = fp[1], f10 = fp[W], f11 = fp[W + 1];
        float r = f00 * w00 + f10 * w10 + f01 * w01 + f11 * w11;
        __builtin_nontemporal_store(r, op);
        fp += HW; op += N;
    }
}

extern "C" void kernel_launch(void* const* d_in, const int* in_sizes, int n_in,
                              void* d_out, int out_size, void* d_ws, size_t ws_size,
                              hipStream_t stream)
{
    const float* fmap = (const float*)d_in[0];
    const float* uv   = (const float*)d_in[1];
    const int*   dsp  = (const int*)d_in[2];
    float*       out  = (float*)d_out;

    int N = in_sizes[1] / 2;

    size_t need = WS_SORTED + (size_t)N * 16;
    if (ws_size < need) {
        int NP  = (N + 1) / 2;
        int NBX = (N + 255) / 256;
        (void)NP;
        dim3 grid(NBX * F_CG);
        fallback_kernel<<<grid, dim3(256), 0, stream>>>(fmap, uv, dsp, out, N, NBX);
        return;
    }

    char* ws = (char*)d_ws;
    int*   hist   = (int*)(ws + WS_HIST);
    int*   cursor = (int*)(ws + WS_CURSOR);
    int*   starts = (int*)(ws + WS_STARTS);
    uint4* sorted = (uint4*)(ws + WS_SORTED);

    int nb = (N + 255) / 256;
    k0_zero<<<1, 512, 0, stream>>>(hist, cursor);
    k1_count<<<nb, 256, 0, stream>>>(uv, dsp, hist, N);
    k2_scan<<<1, 512, 0, stream>>>(hist, starts, cursor);
    k3_scatter<<<nb, 256, 0, stream>>>(uv, dsp, cursor, sorted, N);
    k4_resample<<<NBINS * NCG, 256, 0, stream>>>(fmap, sorted, starts, out, N);
}

// Round 6
// 407.238 us; speedup vs baseline: 2.9967x; 2.9967x over previous
//
#include <hip/hip_runtime.h>

// Bilinear resampling: feature_map [C,H,W] fp32, target_uv [N,2] fp32, downscale (int scalar)
// out [C,N] fp32.
//
// R6 pipeline: bin points (32x32 px) -> LDS-staged gather computing mid[p][c]
// (point-major, coalesced full-sector writes) -> both-sides-coalesced permute
// mid[sorted p] -> out[C][N] via LDS transpose.
constexpr int C = 128, H = 376, W = 1248;
constexpr int HW = H * W;

constexpr int BIN  = 32;
constexpr int BU   = (W + BIN - 1) / BIN;   // 39
constexpr int BV   = (H + BIN - 1) / BIN;   // 12
constexpr int NBINS = BU * BV;              // 468
constexpr int CPG  = 8;                     // channels per k4 block
constexpr int NCG  = C / CPG;               // 16
constexpr int RW   = BIN + 1;               // 33
constexpr int RH   = BIN + 1;               // 33
constexpr int RS   = RW + 1;                // 34 (pad)
constexpr int CH_STRIDE = RH * RS;          // 1122 floats

typedef float vfloat4 __attribute__((ext_vector_type(4)));

__global__ __launch_bounds__(512) void k0_zero(int* hist, int* cursor) {
    for (int i = threadIdx.x; i < NBINS; i += 512) { hist[i] = 0; cursor[i] = 0; }
}

__global__ __launch_bounds__(256) void k1_count(const float* __restrict__ uv,
                                                const int* __restrict__ dsp,
                                                int* __restrict__ hist, int N) {
    int n = blockIdx.x * 256 + threadIdx.x;
    if (n >= N) return;
    float dsf = (float)dsp[0];
    float2 p = ((const float2*)uv)[n];
    int ul = (int)(p.x / dsf);
    int vl = (int)(p.y / dsf);
    int bin = (vl >> 5) * BU + (ul >> 5);
    atomicAdd(hist + bin, 1);
}

__global__ __launch_bounds__(512) void k2_scan(const int* __restrict__ hist,
                                               int* __restrict__ starts,
                                               int* __restrict__ cursor) {
    __shared__ int sh[512];
    int t = threadIdx.x;
    sh[t] = (t < NBINS) ? hist[t] : 0;
    __syncthreads();
    for (int off = 1; off < 512; off <<= 1) {
        int v = (t >= off) ? sh[t - off] : 0;
        __syncthreads();
        sh[t] += v;
        __syncthreads();
    }
    if (t < NBINS) {
        starts[t + 1] = sh[t];
        cursor[t] = sh[t] - hist[t];   // exclusive
        if (t == 0) starts[0] = 0;
    }
}

__global__ __launch_bounds__(256) void k3_scatter(const float* __restrict__ uv,
                                                  const int* __restrict__ dsp,
                                                  int* __restrict__ cursor,
                                                  uint4* __restrict__ sorted,
                                                  int* __restrict__ inv, int N) {
    int n = blockIdx.x * 256 + threadIdx.x;
    if (n >= N) return;
    float dsf = (float)dsp[0];
    float2 p = ((const float2*)uv)[n];
    float u = p.x / dsf, v = p.y / dsf;
    int ul = (int)u, vl = (int)v;
    float du = u - (float)ul, dv = v - (float)vl;
    int bin = (vl >> 5) * BU + (ul >> 5);
    int pos = atomicAdd(cursor + bin, 1);
    uint4 rec;
    rec.x = (unsigned)(ul | (vl << 16));
    rec.y = __float_as_uint(du);
    rec.z = __float_as_uint(dv);
    rec.w = (unsigned)n;
    sorted[pos] = rec;
    inv[n] = pos;                 // coalesced: dest-side permutation index
}

// k4: (bin, channel-group) blocks. LDS-stage the 33x33 region x 8 channels,
// serve the bin's points from LDS, write mid[p][cb..cb+7] (point-major, full sectors).
__global__ __launch_bounds__(256) void k4_resample(const float* __restrict__ fmap,
                                                   const uint4* __restrict__ sorted,
                                                   const int* __restrict__ starts,
                                                   float* __restrict__ mid, int N) {
    __shared__ float lds[CPG * CH_STRIDE];   // 35,904 B

    int bin = blockIdx.x >> 4;      // / NCG
    int cg  = blockIdx.x & 15;      // % NCG
    int bu  = bin % BU;
    int bv  = bin / BU;
    int u0  = bu * BIN;
    int v0  = bv * BIN;
    int cb  = cg * CPG;
    int tid = threadIdx.x;

#pragma unroll
    for (int c = 0; c < CPG; ++c) {
        const float* src = fmap + (size_t)(cb + c) * HW;
        for (int idx = tid; idx < RH * RW; idx += 256) {
            int r  = idx / RW;
            int cc = idx - r * RW;
            int gr = min(v0 + r, H - 1);
            int gc = min(u0 + cc, W - 1);
            lds[c * CH_STRIDE + r * RS + cc] = src[(size_t)gr * W + gc];
        }
    }
    __syncthreads();

    int s = starts[bin], e = starts[bin + 1];
    for (int p = s + tid; p < e; p += 256) {
        uint4 pt = sorted[p];
        int ul = (int)(pt.x & 0xffffu);
        int vl = (int)(pt.x >> 16);
        float du = __uint_as_float(pt.y);
        float dv = __uint_as_float(pt.z);

        float w00 = (1.0f - dv) * (1.0f - du);
        float w10 = dv * (1.0f - du);
        float w01 = (1.0f - dv) * du;
        float w11 = dv * du;

        const float* base = &lds[(vl - v0) * RS + (ul - u0)];
        float r[CPG];
#pragma unroll
        for (int c = 0; c < CPG; ++c) {
            float f00 = base[c * CH_STRIDE];
            float f01 = base[c * CH_STRIDE + 1];
            float f10 = base[c * CH_STRIDE + RS];
            float f11 = base[c * CH_STRIDE + RS + 1];
            r[c] = f00 * w00 + f10 * w10 + f01 * w01 + f11 * w11;
        }
        float* mp = mid + (size_t)p * C + cb;
        vfloat4 lo = {r[0], r[1], r[2], r[3]};
        vfloat4 hi = {r[4], r[5], r[6], r[7]};
        *(vfloat4*)mp = lo;            // cached: mid re-read by k5 (L3-resident)
        *(vfloat4*)(mp + 4) = hi;
    }
}

// k5: both-sides-coalesced permutation. 64 dest points per block:
// gather each point's contiguous 512B channel-row from mid, LDS-transpose,
// write out[c][n0..n0+63] in contiguous 256B runs.
__global__ __launch_bounds__(256) void k5_permute(const float* __restrict__ mid,
                                                  const int* __restrict__ inv,
                                                  float* __restrict__ out, int N) {
    __shared__ float tile[64][C + 1];   // 33,024 B
    __shared__ int   sp[64];
    int n0 = blockIdx.x * 64;
    int t  = threadIdx.x;
    int cnt = min(64, N - n0);

    if (t < 64) sp[t] = (t < cnt) ? inv[n0 + t] : 0;
    __syncthreads();

    // 8 rounds x 8 points: lanes (t&31) cover the 128-ch row (512B coalesced).
    for (int r8 = 0; r8 < 8; ++r8) {
        int j  = r8 * 8 + (t >> 5);
        int ch = (t & 31) * 4;
        if (j < cnt) {
            vfloat4 v = *(const vfloat4*)(mid + (size_t)sp[j] * C + ch);
            tile[j][ch]     = v.x;
            tile[j][ch + 1] = v.y;
            tile[j][ch + 2] = v.z;
            tile[j][ch + 3] = v.w;
        }
    }
    __syncthreads();

    // 32 rounds x 4 channels: lanes j=0..63 write contiguous 256B per channel row.
    int j = t & 63;
    for (int s = 0; s < 32; ++s) {
        int c = s * 4 + (t >> 6);
        if (j < cnt)
            __builtin_nontemporal_store(tile[j][c], out + (size_t)c * N + n0 + j);
    }
}

// ---- Fallback (R2 structure, 301us known-good) if ws too small ----
constexpr int F_CPG = 2;
constexpr int F_CG  = C / F_CPG;
constexpr int F_GPX = F_CG / 8;

__global__ __launch_bounds__(256) void fallback_kernel(
    const float* __restrict__ fmap, const float* __restrict__ uv,
    const int* __restrict__ dsp, float* __restrict__ out, int N, int NBX)
{
    int bid = blockIdx.x;
    int xcd = bid & 7;
    int jj  = bid >> 3;
    int g_local = jj / NBX;
    int nb      = jj - g_local * NBX;
    int g   = xcd * F_GPX + g_local;

    int n = nb * 256 + threadIdx.x;
    if (n >= N) return;

    float dsf = (float)dsp[0];
    float2 p = ((const float2*)uv)[n];
    float u = p.x / dsf, v = p.y / dsf;
    int u_lo = (int)u, v_lo = (int)v;
    float du = u - (float)u_lo, dv = v - (float)v_lo;

    float w00 = (1.0f - dv) * (1.0f - du);
    float w10 = dv * (1.0f - du);
    float w01 = (1.0f - dv) * du;
    float w11 = dv * du;

    int cbase = g * F_CPG;
    const float* fp = fmap + (size_t)cbase * HW + (size_t)v_lo * W + u_lo;
    float*       op = out  + (size_t)cbase * N + n;
#pragma unroll
    for (int c = 0; c < F_CPG; ++c) {
        float f00 = fp[0], f01 = fp[1], f10 = fp[W], f11 = fp[W + 1];
        float r = f00 * w00 + f10 * w10 + f01 * w01 + f11 * w11;
        __builtin_nontemporal_store(r, op);
        fp += HW; op += N;
    }
}

extern "C" void kernel_launch(void* const* d_in, const int* in_sizes, int n_in,
                              void* d_out, int out_size, void* d_ws, size_t ws_size,
                              hipStream_t stream)
{
    const float* fmap = (const float*)d_in[0];
    const float* uv   = (const float*)d_in[1];
    const int*   dsp  = (const int*)d_in[2];
    float*       out  = (float*)d_out;

    int N = in_sizes[1] / 2;

    // ws layout
    size_t off_hist   = 0;
    size_t off_cursor = 4096;
    size_t off_starts = 8192;
    size_t off_inv    = 16384;
    size_t off_sorted = off_inv + (((size_t)N * 4 + 255) & ~(size_t)255);
    size_t off_mid    = off_sorted + (((size_t)N * 16 + 255) & ~(size_t)255);
    size_t need       = off_mid + (size_t)N * C * 4;

    if (ws_size < need) {
        int NBX = (N + 255) / 256;
        dim3 grid(NBX * F_CG);
        fallback_kernel<<<grid, dim3(256), 0, stream>>>(fmap, uv, dsp, out, N, NBX);
        return;
    }

    char* ws = (char*)d_ws;
    int*   hist   = (int*)(ws + off_hist);
    int*   cursor = (int*)(ws + off_cursor);
    int*   starts = (int*)(ws + off_starts);
    int*   inv    = (int*)(ws + off_inv);
    uint4* sorted = (uint4*)(ws + off_sorted);
    float* mid    = (float*)(ws + off_mid);

    int nb = (N + 255) / 256;
    k0_zero<<<1, 512, 0, stream>>>(hist, cursor);
    k1_count<<<nb, 256, 0, stream>>>(uv, dsp, hist, N);
    k2_scan<<<1, 512, 0, stream>>>(hist, starts, cursor);
    k3_scatter<<<nb, 256, 0, stream>>>(uv, dsp, cursor, sorted, inv, N);
    k4_resample<<<NBINS * NCG, 256, 0, stream>>>(fmap, sorted, starts, mid, N);
    k5_permute<<<(N + 63) / 64, 256, 0, stream>>>(mid, inv, out, N);
}

// Round 7
// 297.241 us; speedup vs baseline: 4.1056x; 1.3701x over previous
//
#include <hip/hip_runtime.h>

// Bilinear resampling: feature_map [C,H,W] fp32, target_uv [N,2] fp32, downscale (int scalar)
// out [C,N] fp32.
//
// R7: R6 pipeline + latency fixes.
//  - k4: batched register staging (break load->ds_write serialization),
//        CPG=4 (19KB LDS -> 8 blocks/CU, 32 waves), chunk-linear LDS layout,
//        gather via one base VGPR + immediate ds offsets.
//  - k5: batched register gather before LDS transpose.
//  - k1: LDS-aggregated histogram.
constexpr int C = 128, H = 376, W = 1248;
constexpr int HW = H * W;

constexpr int BIN  = 32;
constexpr int BU   = (W + BIN - 1) / BIN;   // 39
constexpr int BV   = (H + BIN - 1) / BIN;   // 12
constexpr int NBINS = BU * BV;              // 468
constexpr int CPG  = 4;                     // channels per k4 block
constexpr int NCG  = C / CPG;               // 32
constexpr int RWP  = 36;                    // padded region row (33 used + 3 garbage), 9 chunks
constexpr int CHROW = 9;                    // float4 chunks per row
constexpr int ROWS = 33;
constexpr int CH_CHUNKS = ROWS * CHROW;     // 297 chunks per channel
constexpr int BLK_CHUNKS = CPG * CH_CHUNKS; // 1188 chunks per block
constexpr int CH_F = CH_CHUNKS * 4;         // 1188 floats per channel

typedef float vfloat4 __attribute__((ext_vector_type(4)));

__global__ __launch_bounds__(512) void k0_zero(int* hist, int* cursor) {
    for (int i = threadIdx.x; i < NBINS; i += 512) { hist[i] = 0; cursor[i] = 0; }
}

__global__ __launch_bounds__(256) void k1_count(const float* __restrict__ uv,
                                                const int* __restrict__ dsp,
                                                int* __restrict__ hist, int N) {
    __shared__ int lh[NBINS];
    for (int i = threadIdx.x; i < NBINS; i += 256) lh[i] = 0;
    __syncthreads();
    int n = blockIdx.x * 256 + threadIdx.x;
    if (n < N) {
        float dsf = (float)dsp[0];
        float2 p = ((const float2*)uv)[n];
        int ul = (int)(p.x / dsf);
        int vl = (int)(p.y / dsf);
        atomicAdd(&lh[(vl >> 5) * BU + (ul >> 5)], 1);
    }
    __syncthreads();
    for (int i = threadIdx.x; i < NBINS; i += 256)
        if (lh[i]) atomicAdd(hist + i, lh[i]);
}

__global__ __launch_bounds__(512) void k2_scan(const int* __restrict__ hist,
                                               int* __restrict__ starts,
                                               int* __restrict__ cursor) {
    __shared__ int sh[512];
    int t = threadIdx.x;
    sh[t] = (t < NBINS) ? hist[t] : 0;
    __syncthreads();
    for (int off = 1; off < 512; off <<= 1) {
        int v = (t >= off) ? sh[t - off] : 0;
        __syncthreads();
        sh[t] += v;
        __syncthreads();
    }
    if (t < NBINS) {
        starts[t + 1] = sh[t];
        cursor[t] = sh[t] - hist[t];   // exclusive
        if (t == 0) starts[0] = 0;
    }
}

__global__ __launch_bounds__(256) void k3_scatter(const float* __restrict__ uv,
                                                  const int* __restrict__ dsp,
                                                  int* __restrict__ cursor,
                                                  uint4* __restrict__ sorted,
                                                  int* __restrict__ inv, int N) {
    int n = blockIdx.x * 256 + threadIdx.x;
    if (n >= N) return;
    float dsf = (float)dsp[0];
    float2 p = ((const float2*)uv)[n];
    float u = p.x / dsf, v = p.y / dsf;
    int ul = (int)u, vl = (int)v;
    float du = u - (float)ul, dv = v - (float)vl;
    int bin = (vl >> 5) * BU + (ul >> 5);
    int pos = atomicAdd(cursor + bin, 1);
    uint4 rec;
    rec.x = (unsigned)(ul | (vl << 16));
    rec.y = __float_as_uint(du);
    rec.z = __float_as_uint(dv);
    rec.w = (unsigned)n;
    sorted[pos] = rec;
    inv[n] = pos;                 // coalesced: dest-side permutation index
}

// k4: (bin, channel-group) blocks. Batched-register staging of the 33x36(pad) x 4ch
// region, then LDS gather, write mid[p][cb..cb+3] (point-major, full sectors).
__global__ __launch_bounds__(256) void k4_resample(const float* __restrict__ fmap,
                                                   const uint4* __restrict__ sorted,
                                                   const int* __restrict__ starts,
                                                   float* __restrict__ mid, int N) {
    __shared__ float lds[BLK_CHUNKS * 4];   // 19,008 B

    int bin = blockIdx.x >> 5;      // / NCG
    int cg  = blockIdx.x & 31;      // % NCG
    int bu  = bin % BU;
    int bv  = bin / BU;
    int u0  = bu * BIN;
    int v0  = bv * BIN;
    int cb  = cg * CPG;
    int tid = threadIdx.x;

    // ---- staging: issue ALL loads into regs first, then write LDS ----
    vfloat4 stg[5];
#pragma unroll
    for (int i = 0; i < 5; ++i) {
        int k = tid + i * 256;
        if (k < BLK_CHUNKS) {
            int ch  = k / CH_CHUNKS;
            int rem = k - ch * CH_CHUNKS;
            int r   = rem / CHROW;
            int c4  = rem - r * CHROW;
            int gr  = min(v0 + r, H - 1);
            int gc  = min(u0 + c4 * 4, W - 4);   // keep 16B load in-row/in-bounds
            stg[i] = *(const vfloat4*)(fmap + (size_t)(cb + ch) * HW + (size_t)gr * W + gc);
        }
    }
#pragma unroll
    for (int i = 0; i < 5; ++i) {
        int k = tid + i * 256;
        if (k < BLK_CHUNKS)
            *(vfloat4*)&lds[k * 4] = stg[i];     // chunk-linear layout: offset = 16B * k
    }
    __syncthreads();

    // ---- gather from LDS ----
    int s = starts[bin], e = starts[bin + 1];
    for (int p = s + tid; p < e; p += 256) {
        uint4 pt = sorted[p];
        int ul = (int)(pt.x & 0xffffu);
        int vl = (int)(pt.x >> 16);
        float du = __uint_as_float(pt.y);
        float dv = __uint_as_float(pt.z);

        float w00 = (1.0f - dv) * (1.0f - du);
        float w10 = dv * (1.0f - du);
        float w01 = (1.0f - dv) * du;
        float w11 = dv * du;

        const float* base = &lds[(vl - v0) * RWP + (ul - u0)];
        float r[CPG];
#pragma unroll
        for (int c = 0; c < CPG; ++c) {
            float f00 = base[c * CH_F];
            float f01 = base[c * CH_F + 1];
            float f10 = base[c * CH_F + RWP];
            float f11 = base[c * CH_F + RWP + 1];
            r[c] = f00 * w00 + f10 * w10 + f01 * w01 + f11 * w11;
        }
        vfloat4 rv = {r[0], r[1], r[2], r[3]};
        *(vfloat4*)(mid + (size_t)p * C + cb) = rv;   // cached: re-read by k5 via L3
    }
}

// k5: both-sides-coalesced permutation. 64 dest points per block:
// batched gather of each point's contiguous 512B channel-row from mid,
// LDS-transpose, write out[c][n0..n0+63] in contiguous 256B runs.
__global__ __launch_bounds__(256) void k5_permute(const float* __restrict__ mid,
                                                  const int* __restrict__ inv,
                                                  float* __restrict__ out, int N) {
    __shared__ float tile[64][C + 1];   // 33,024 B
    __shared__ int   sp[64];
    int n0 = blockIdx.x * 64;
    int t  = threadIdx.x;
    int cnt = min(64, N - n0);

    if (t < 64) sp[t] = (t < cnt) ? inv[n0 + t] : 0;
    __syncthreads();

    int ch = (t & 31) * 4;
    // Batch all 8 global loads into regs first (8 outstanding per thread).
    vfloat4 g[8];
#pragma unroll
    for (int r8 = 0; r8 < 8; ++r8) {
        int j = r8 * 8 + (t >> 5);
        if (j < cnt)
            g[r8] = *(const vfloat4*)(mid + (size_t)sp[j] * C + ch);
    }
#pragma unroll
    for (int r8 = 0; r8 < 8; ++r8) {
        int j = r8 * 8 + (t >> 5);
        if (j < cnt) {
            tile[j][ch]     = g[r8].x;
            tile[j][ch + 1] = g[r8].y;
            tile[j][ch + 2] = g[r8].z;
            tile[j][ch + 3] = g[r8].w;
        }
    }
    __syncthreads();

    // 32 rounds x 4 channels: lanes j=0..63 write contiguous 256B per channel row.
    int j = t & 63;
    for (int s = 0; s < 32; ++s) {
        int c = s * 4 + (t >> 6);
        if (j < cnt)
            __builtin_nontemporal_store(tile[j][c], out + (size_t)c * N + n0 + j);
    }
}

// ---- Fallback (R2 structure, known-good) if ws too small ----
constexpr int F_CPG = 2;
constexpr int F_CG  = C / F_CPG;
constexpr int F_GPX = F_CG / 8;

__global__ __launch_bounds__(256) void fallback_kernel(
    const float* __restrict__ fmap, const float* __restrict__ uv,
    const int* __restrict__ dsp, float* __restrict__ out, int N, int NBX)
{
    int bid = blockIdx.x;
    int xcd = bid & 7;
    int jj  = bid >> 3;
    int g_local = jj / NBX;
    int nb      = jj - g_local * NBX;
    int g   = xcd * F_GPX + g_local;

    int n = nb * 256 + threadIdx.x;
    if (n >= N) return;

    float dsf = (float)dsp[0];
    float2 p = ((const float2*)uv)[n];
    float u = p.x / dsf, v = p.y / dsf;
    int u_lo = (int)u, v_lo = (int)v;
    float du = u - (float)u_lo, dv = v - (float)v_lo;

    float w00 = (1.0f - dv) * (1.0f - du);
    float w10 = dv * (1.0f - du);
    float w01 = (1.0f - dv) * du;
    float w11 = dv * du;

    int cbase = g * F_CPG;
    const float* fp = fmap + (size_t)cbase * HW + (size_t)v_lo * W + u_lo;
    float*       op = out  + (size_t)cbase * N + n;
#pragma unroll
    for (int c = 0; c < F_CPG; ++c) {
        float f00 = fp[0], f01 = fp[1], f10 = fp[W], f11 = fp[W + 1];
        float r = f00 * w00 + f10 * w10 + f01 * w01 + f11 * w11;
        __builtin_nontemporal_store(r, op);
        fp += HW; op += N;
    }
}

extern "C" void kernel_launch(void* const* d_in, const int* in_sizes, int n_in,
                              void* d_out, int out_size, void* d_ws, size_t ws_size,
                              hipStream_t stream)
{
    const float* fmap = (const float*)d_in[0];
    const float* uv   = (const float*)d_in[1];
    const int*   dsp  = (const int*)d_in[2];
    float*       out  = (float*)d_out;

    int N = in_sizes[1] / 2;

    // ws layout
    size_t off_hist   = 0;
    size_t off_cursor = 4096;
    size_t off_starts = 8192;
    size_t off_inv    = 16384;
    size_t off_sorted = off_inv + (((size_t)N * 4 + 255) & ~(size_t)255);
    size_t off_mid    = off_sorted + (((size_t)N * 16 + 255) & ~(size_t)255);
    size_t need       = off_mid + (size_t)N * C * 4;

    if (ws_size < need) {
        int NBX = (N + 255) / 256;
        dim3 grid(NBX * F_CG);
        fallback_kernel<<<grid, dim3(256), 0, stream>>>(fmap, uv, dsp, out, N, NBX);
        return;
    }

    char* ws = (char*)d_ws;
    int*   hist   = (int*)(ws + off_hist);
    int*   cursor = (int*)(ws + off_cursor);
    int*   starts = (int*)(ws + off_starts);
    int*   inv    = (int*)(ws + off_inv);
    uint4* sorted = (uint4*)(ws + off_sorted);
    float* mid    = (float*)(ws + off_mid);

    int nb = (N + 255) / 256;
    k0_zero<<<1, 512, 0, stream>>>(hist, cursor);
    k1_count<<<nb, 256, 0, stream>>>(uv, dsp, hist, N);
    k2_scan<<<1, 512, 0, stream>>>(hist, starts, cursor);
    k3_scatter<<<nb, 256, 0, stream>>>(uv, dsp, cursor, sorted, inv, N);
    k4_resample<<<NBINS * NCG, 256, 0, stream>>>(fmap, sorted, starts, mid, N);
    k5_permute<<<(N + 63) / 64, 256, 0, stream>>>(mid, inv, out, N);
}

// Round 8
// 236.131 us; speedup vs baseline: 5.1682x; 1.2588x over previous
//
#include <hip/hip_runtime.h>

// Bilinear resampling: feature_map [C,H,W] fp32, target_uv [N,2] fp32, downscale (int scalar)
// out [C,N] fp32.
//
// R8: bin(24px) -> LDS-staged gather (CPG=8, batched reg staging, 22.4KB LDS,
// 7 blocks/CU) writing mid[p][c] point-major (32B/point full-sector stores)
// -> both-sides-coalesced permute mid -> out[C][N].
constexpr int C = 128, H = 376, W = 1248;
constexpr int HW = H * W;

constexpr int BIN  = 24;
constexpr int BU   = (W + BIN - 1) / BIN;   // 52
constexpr int BV   = (H + BIN - 1) / BIN;   // 16
constexpr int NBINS = BU * BV;              // 832
constexpr int CPG  = 8;                     // channels per k4 block
constexpr int NCG  = C / CPG;               // 16
constexpr int ROWS = BIN + 1;               // 25 region rows
constexpr int CHROW = 7;                    // float4 chunks per row (28 floats >= 25 needed)
constexpr int RWF  = CHROW * 4;             // 28 floats row stride
constexpr int CH_CHUNKS = ROWS * CHROW;     // 175 chunks per channel
constexpr int BLK_CHUNKS = CPG * CH_CHUNKS; // 1400 chunks per block
constexpr int CH_F = CH_CHUNKS * 4;         // 700 floats per channel
constexpr int STG = (BLK_CHUNKS + 255) / 256; // 6 staging registers (float4)

typedef float vfloat4 __attribute__((ext_vector_type(4)));

__global__ __launch_bounds__(512) void k0_zero(int* hist, int* cursor) {
    for (int i = threadIdx.x; i < NBINS; i += 512) { hist[i] = 0; cursor[i] = 0; }
}

__global__ __launch_bounds__(256) void k1_count(const float* __restrict__ uv,
                                                const int* __restrict__ dsp,
                                                int* __restrict__ hist, int N) {
    __shared__ int lh[NBINS];
    for (int i = threadIdx.x; i < NBINS; i += 256) lh[i] = 0;
    __syncthreads();
    int n = blockIdx.x * 256 + threadIdx.x;
    if (n < N) {
        float dsf = (float)dsp[0];
        float2 p = ((const float2*)uv)[n];
        int ul = (int)(p.x / dsf);
        int vl = (int)(p.y / dsf);
        atomicAdd(&lh[(vl / BIN) * BU + (ul / BIN)], 1);
    }
    __syncthreads();
    for (int i = threadIdx.x; i < NBINS; i += 256)
        if (lh[i]) atomicAdd(hist + i, lh[i]);
}

__global__ __launch_bounds__(1024) void k2_scan(const int* __restrict__ hist,
                                                int* __restrict__ starts,
                                                int* __restrict__ cursor) {
    __shared__ int sh[1024];
    int t = threadIdx.x;
    sh[t] = (t < NBINS) ? hist[t] : 0;
    __syncthreads();
    for (int off = 1; off < 1024; off <<= 1) {
        int v = (t >= off) ? sh[t - off] : 0;
        __syncthreads();
        sh[t] += v;
        __syncthreads();
    }
    if (t < NBINS) {
        starts[t + 1] = sh[t];
        cursor[t] = sh[t] - hist[t];   // exclusive
        if (t == 0) starts[0] = 0;
    }
}

__global__ __launch_bounds__(256) void k3_scatter(const float* __restrict__ uv,
                                                  const int* __restrict__ dsp,
                                                  int* __restrict__ cursor,
                                                  uint4* __restrict__ sorted,
                                                  int* __restrict__ inv, int N) {
    int n = blockIdx.x * 256 + threadIdx.x;
    if (n >= N) return;
    float dsf = (float)dsp[0];
    float2 p = ((const float2*)uv)[n];
    float u = p.x / dsf, v = p.y / dsf;
    int ul = (int)u, vl = (int)v;
    float du = u - (float)ul, dv = v - (float)vl;
    int bin = (vl / BIN) * BU + (ul / BIN);
    int pos = atomicAdd(cursor + bin, 1);
    uint4 rec;
    rec.x = (unsigned)(ul | (vl << 16));
    rec.y = __float_as_uint(du);
    rec.z = __float_as_uint(dv);
    rec.w = (unsigned)n;
    sorted[pos] = rec;
    inv[n] = pos;                 // coalesced: dest-side permutation index
}

// k4: (bin, channel-group) blocks. Batched-register staging of 25x28(pad) x 8ch,
// LDS gather, write mid[p][cb..cb+7] (point-major, 32B full-sector store).
__global__ __launch_bounds__(256) void k4_resample(const float* __restrict__ fmap,
                                                   const uint4* __restrict__ sorted,
                                                   const int* __restrict__ starts,
                                                   float* __restrict__ mid, int N) {
    __shared__ float lds[BLK_CHUNKS * 4];   // 22,400 B -> 7 blocks/CU

    int bin = blockIdx.x >> 4;      // / NCG
    int cg  = blockIdx.x & 15;      // % NCG
    int bu  = bin % BU;
    int bv  = bin / BU;
    int u0  = bu * BIN;
    int v0  = bv * BIN;
    int cb  = cg * CPG;
    int tid = threadIdx.x;

    // ---- staging: issue ALL loads into regs first, then write LDS ----
    vfloat4 stg[STG];
#pragma unroll
    for (int i = 0; i < STG; ++i) {
        int k = tid + i * 256;
        if (k < BLK_CHUNKS) {
            int ch  = k / CH_CHUNKS;           // const-div -> mulhi
            int rem = k - ch * CH_CHUNKS;
            int r   = rem / CHROW;
            int c4  = rem - r * CHROW;
            int gr  = min(v0 + r, H - 1);
            int gc  = min(u0 + c4 * 4, W - 4);   // keep 16B load in-bounds
            stg[i] = *(const vfloat4*)(fmap + (size_t)(cb + ch) * HW + (size_t)gr * W + gc);
        }
    }
#pragma unroll
    for (int i = 0; i < STG; ++i) {
        int k = tid + i * 256;
        if (k < BLK_CHUNKS)
            *(vfloat4*)&lds[k * 4] = stg[i];     // chunk-linear: float idx = ch*700 + r*28 + col
    }
    __syncthreads();

    // ---- gather from LDS ----
    int s = starts[bin], e = starts[bin + 1];
    for (int p = s + tid; p < e; p += 256) {
        uint4 pt = sorted[p];
        int ul = (int)(pt.x & 0xffffu);
        int vl = (int)(pt.x >> 16);
        float du = __uint_as_float(pt.y);
        float dv = __uint_as_float(pt.z);

        float w00 = (1.0f - dv) * (1.0f - du);
        float w10 = dv * (1.0f - du);
        float w01 = (1.0f - dv) * du;
        float w11 = dv * du;

        const float* base = &lds[(vl - v0) * RWF + (ul - u0)];
        float r[CPG];
#pragma unroll
        for (int c = 0; c < CPG; ++c) {
            float f00 = base[c * CH_F];
            float f01 = base[c * CH_F + 1];
            float f10 = base[c * CH_F + RWF];
            float f11 = base[c * CH_F + RWF + 1];
            r[c] = f00 * w00 + f10 * w10 + f01 * w01 + f11 * w11;
        }
        float* mp = mid + (size_t)p * C + cb;
        vfloat4 lo = {r[0], r[1], r[2], r[3]};
        vfloat4 hi = {r[4], r[5], r[6], r[7]};
        *(vfloat4*)mp = lo;           // 32B to one line: full-sector write
        *(vfloat4*)(mp + 4) = hi;
    }
}

// k5: both-sides-coalesced permutation. 64 dest points per block.
__global__ __launch_bounds__(256) void k5_permute(const float* __restrict__ mid,
                                                  const int* __restrict__ inv,
                                                  float* __restrict__ out, int N) {
    __shared__ float tile[64][C + 1];   // 33,024 B
    __shared__ int   sp[64];
    int n0 = blockIdx.x * 64;
    int t  = threadIdx.x;
    int cnt = min(64, N - n0);

    if (t < 64) sp[t] = (t < cnt) ? inv[n0 + t] : 0;
    __syncthreads();

    int ch = (t & 31) * 4;
    vfloat4 g[8];
#pragma unroll
    for (int r8 = 0; r8 < 8; ++r8) {
        int j = r8 * 8 + (t >> 5);
        if (j < cnt)
            g[r8] = *(const vfloat4*)(mid + (size_t)sp[j] * C + ch);
    }
#pragma unroll
    for (int r8 = 0; r8 < 8; ++r8) {
        int j = r8 * 8 + (t >> 5);
        if (j < cnt) {
            tile[j][ch]     = g[r8].x;
            tile[j][ch + 1] = g[r8].y;
            tile[j][ch + 2] = g[r8].z;
            tile[j][ch + 3] = g[r8].w;
        }
    }
    __syncthreads();

    int j = t & 63;
    for (int s = 0; s < 32; ++s) {
        int c = s * 4 + (t >> 6);
        if (j < cnt)
            __builtin_nontemporal_store(tile[j][c], out + (size_t)c * N + n0 + j);
    }
}

// ---- Fallback (R2 structure, known-good) if ws too small ----
constexpr int F_CPG = 2;
constexpr int F_CG  = C / F_CPG;
constexpr int F_GPX = F_CG / 8;

__global__ __launch_bounds__(256) void fallback_kernel(
    const float* __restrict__ fmap, const float* __restrict__ uv,
    const int* __restrict__ dsp, float* __restrict__ out, int N, int NBX)
{
    int bid = blockIdx.x;
    int xcd = bid & 7;
    int jj  = bid >> 3;
    int g_local = jj / NBX;
    int nb      = jj - g_local * NBX;
    int g   = xcd * F_GPX + g_local;

    int n = nb * 256 + threadIdx.x;
    if (n >= N) return;

    float dsf = (float)dsp[0];
    float2 p = ((const float2*)uv)[n];
    float u = p.x / dsf, v = p.y / dsf;
    int u_lo = (int)u, v_lo = (int)v;
    float du = u - (float)u_lo, dv = v - (float)v_lo;

    float w00 = (1.0f - dv) * (1.0f - du);
    float w10 = dv * (1.0f - du);
    float w01 = (1.0f - dv) * du;
    float w11 = dv * du;

    int cbase = g * F_CPG;
    const float* fp = fmap + (size_t)cbase * HW + (size_t)v_lo * W + u_lo;
    float*       op = out  + (size_t)cbase * N + n;
#pragma unroll
    for (int c = 0; c < F_CPG; ++c) {
        float f00 = fp[0], f01 = fp[1], f10 = fp[W], f11 = fp[W + 1];
        float r = f00 * w00 + f10 * w10 + f01 * w01 + f11 * w11;
        __builtin_nontemporal_store(r, op);
        fp += HW; op += N;
    }
}

extern "C" void kernel_launch(void* const* d_in, const int* in_sizes, int n_in,
                              void* d_out, int out_size, void* d_ws, size_t ws_size,
                              hipStream_t stream)
{
    const float* fmap = (const float*)d_in[0];
    const float* uv   = (const float*)d_in[1];
    const int*   dsp  = (const int*)d_in[2];
    float*       out  = (float*)d_out;

    int N = in_sizes[1] / 2;

    // ws layout
    size_t off_hist   = 0;
    size_t off_cursor = 4096;
    size_t off_starts = 8192;      // NBINS+1 = 833 ints = 3332 B < 8192
    size_t off_inv    = 16384;
    size_t off_sorted = off_inv + (((size_t)N * 4 + 255) & ~(size_t)255);
    size_t off_mid    = off_sorted + (((size_t)N * 16 + 255) & ~(size_t)255);
    size_t need       = off_mid + (size_t)N * C * 4;

    if (ws_size < need) {
        int NBX = (N + 255) / 256;
        dim3 grid(NBX * F_CG);
        fallback_kernel<<<grid, dim3(256), 0, stream>>>(fmap, uv, dsp, out, N, NBX);
        return;
    }

    char* ws = (char*)d_ws;
    int*   hist   = (int*)(ws + off_hist);
    int*   cursor = (int*)(ws + off_cursor);
    int*   starts = (int*)(ws + off_starts);
    int*   inv    = (int*)(ws + off_inv);
    uint4* sorted = (uint4*)(ws + off_sorted);
    float* mid    = (float*)(ws + off_mid);

    int nb = (N + 255) / 256;
    k0_zero<<<1, 512, 0, stream>>>(hist, cursor);
    k1_count<<<nb, 256, 0, stream>>>(uv, dsp, hist, N);
    k2_scan<<<1, 1024, 0, stream>>>(hist, starts, cursor);
    k3_scatter<<<nb, 256, 0, stream>>>(uv, dsp, cursor, sorted, inv, N);
    k4_resample<<<NBINS * NCG, 256, 0, stream>>>(fmap, sorted, starts, mid, N);
    k5_permute<<<(N + 63) / 64, 256, 0, stream>>>(mid, inv, out, N);
}

// Round 9
// 222.410 us; speedup vs baseline: 5.4870x; 1.0617x over previous
//
#include <hip/hip_runtime.h>

// Bilinear resampling: feature_map [C,H,W] fp32, target_uv [N,2] fp32, downscale (int scalar)
// out [C,N] fp32.
//
// R9: bin(20px) -> k4: LDS-staged gather, CPG=16, 4 lanes/point, cg-major mid
// (mid[cg][p][16ch]: 64B aligned chunk per point-visit, contiguous across sorted p
// -> streaming stores) -> k5: both-sides-coalesced permute mid -> out[C][N].
constexpr int C = 128, H = 376, W = 1248;
constexpr int HW = H * W;

constexpr int BIN  = 20;
constexpr int BU   = (W + BIN - 1) / BIN;   // 63
constexpr int BV   = (H + BIN - 1) / BIN;   // 19
constexpr int NBINS = BU * BV;              // 1197
constexpr int CPG  = 16;                    // channels per k4 block
constexpr int NCG  = C / CPG;               // 8
constexpr int ROWS = BIN + 1;               // 21 region rows
constexpr int CHROW = 6;                    // float4 chunks per row (24 floats >= 21)
constexpr int RWF  = CHROW * 4;             // 24 floats row stride
constexpr int CH_CHUNKS = ROWS * CHROW;     // 126 chunks per channel
constexpr int BLK_CHUNKS = CPG * CH_CHUNKS; // 2016 chunks per block
constexpr int CH_F = CH_CHUNKS * 4;         // 504 floats per channel
constexpr int STG = (BLK_CHUNKS + 255) / 256; // 8 staging registers (float4)

typedef float vfloat4 __attribute__((ext_vector_type(4)));

__global__ __launch_bounds__(512) void k0_zero(int* hist, int* cursor) {
    for (int i = threadIdx.x; i < NBINS; i += 512) { hist[i] = 0; cursor[i] = 0; }
}

__global__ __launch_bounds__(256) void k1_count(const float* __restrict__ uv,
                                                const int* __restrict__ dsp,
                                                int* __restrict__ hist, int N) {
    __shared__ int lh[NBINS];
    for (int i = threadIdx.x; i < NBINS; i += 256) lh[i] = 0;
    __syncthreads();
    int n = blockIdx.x * 256 + threadIdx.x;
    if (n < N) {
        float dsf = (float)dsp[0];
        float2 p = ((const float2*)uv)[n];
        int ul = (int)(p.x / dsf);
        int vl = (int)(p.y / dsf);
        atomicAdd(&lh[(vl / BIN) * BU + (ul / BIN)], 1);
    }
    __syncthreads();
    for (int i = threadIdx.x; i < NBINS; i += 256)
        if (lh[i]) atomicAdd(hist + i, lh[i]);
}

// 2-chunk carry scan (NBINS=1197 > 1024)
__global__ __launch_bounds__(1024) void k2_scan(const int* __restrict__ hist,
                                                int* __restrict__ starts,
                                                int* __restrict__ cursor) {
    __shared__ int sh[1024];
    __shared__ int carry_s;
    int t = threadIdx.x;
    if (t == 0) { carry_s = 0; starts[0] = 0; }
    __syncthreads();
    constexpr int NCHUNK = (NBINS + 1023) / 1024;
    for (int chunk = 0; chunk < NCHUNK; ++chunk) {
        int i = chunk * 1024 + t;
        int val = (i < NBINS) ? hist[i] : 0;
        sh[t] = val;
        __syncthreads();
        for (int off = 1; off < 1024; off <<= 1) {
            int v = (t >= off) ? sh[t - off] : 0;
            __syncthreads();
            sh[t] += v;
            __syncthreads();
        }
        int cbase = carry_s;
        int incl  = sh[t] + cbase;
        if (i < NBINS) {
            starts[i + 1] = incl;
            cursor[i] = incl - val;      // exclusive
        }
        __syncthreads();                 // all read carry_s before update
        if (t == 1023) carry_s = cbase + sh[1023];
        __syncthreads();
    }
}

__global__ __launch_bounds__(256) void k3_scatter(const float* __restrict__ uv,
                                                  const int* __restrict__ dsp,
                                                  int* __restrict__ cursor,
                                                  uint4* __restrict__ sorted,
                                                  int* __restrict__ inv, int N) {
    int n = blockIdx.x * 256 + threadIdx.x;
    if (n >= N) return;
    float dsf = (float)dsp[0];
    float2 p = ((const float2*)uv)[n];
    float u = p.x / dsf, v = p.y / dsf;
    int ul = (int)u, vl = (int)v;
    float du = u - (float)ul, dv = v - (float)vl;
    int bin = (vl / BIN) * BU + (ul / BIN);
    int pos = atomicAdd(cursor + bin, 1);
    uint4 rec;
    rec.x = (unsigned)(ul | (vl << 16));
    rec.y = __float_as_uint(du);
    rec.z = __float_as_uint(dv);
    rec.w = (unsigned)n;
    sorted[pos] = rec;
    inv[n] = pos;
}

// k4: (bin, cg) blocks. Batched-register staging of 21x24(pad) x 16ch.
// Gather: 4 lanes per point, lane q computes channels q*4..q*4+3, stores one
// 16B chunk -> wave writes 1KB contiguous in cg-major mid.
__global__ __launch_bounds__(256) void k4_resample(const float* __restrict__ fmap,
                                                   const uint4* __restrict__ sorted,
                                                   const int* __restrict__ starts,
                                                   float* __restrict__ mid, int N) {
    __shared__ float lds[BLK_CHUNKS * 4];   // 32,256 B -> 4 blocks/CU

    int bin = blockIdx.x >> 3;      // / NCG
    int cg  = blockIdx.x & 7;       // % NCG
    int bu  = bin % BU;
    int bv  = bin / BU;
    int u0  = bu * BIN;
    int v0  = bv * BIN;
    int cb  = cg * CPG;
    int tid = threadIdx.x;

    // ---- staging: issue ALL loads into regs first, then write LDS ----
    vfloat4 stg[STG];
#pragma unroll
    for (int i = 0; i < STG; ++i) {
        int k = tid + i * 256;
        if (k < BLK_CHUNKS) {
            int ch  = k / CH_CHUNKS;
            int rem = k - ch * CH_CHUNKS;
            int r   = rem / CHROW;
            int c4  = rem - r * CHROW;
            int gr  = min(v0 + r, H - 1);
            int gc  = min(u0 + c4 * 4, W - 4);
            stg[i] = *(const vfloat4*)(fmap + (size_t)(cb + ch) * HW + (size_t)gr * W + gc);
        }
    }
#pragma unroll
    for (int i = 0; i < STG; ++i) {
        int k = tid + i * 256;
        if (k < BLK_CHUNKS)
            *(vfloat4*)&lds[k * 4] = stg[i];   // chunk-linear: ch*504 + r*24 + col
    }
    __syncthreads();

    // ---- gather from LDS: 4 lanes per point ----
    int s = starts[bin], e = starts[bin + 1];
    int q = tid & 3;                 // channel quad within the 16
    const float* chbase = &lds[q * 4 * CH_F];
    for (int p = s + (tid >> 2); p < e; p += 64) {
        uint4 pt = sorted[p];        // 4 lanes read same 16B (line-shared)
        int ul = (int)(pt.x & 0xffffu);
        int vl = (int)(pt.x >> 16);
        float du = __uint_as_float(pt.y);
        float dv = __uint_as_float(pt.z);

        float w00 = (1.0f - dv) * (1.0f - du);
        float w10 = dv * (1.0f - du);
        float w01 = (1.0f - dv) * du;
        float w11 = dv * du;

        const float* base = chbase + (vl - v0) * RWF + (ul - u0);
        float r[4];
#pragma unroll
        for (int c = 0; c < 4; ++c) {
            float f00 = base[c * CH_F];
            float f01 = base[c * CH_F + 1];
            float f10 = base[c * CH_F + RWF];
            float f11 = base[c * CH_F + RWF + 1];
            r[c] = f00 * w00 + f10 * w10 + f01 * w01 + f11 * w11;
        }
        vfloat4 rv = {r[0], r[1], r[2], r[3]};
        // cg-major mid: float offset = (cg*N + p)*16 + q*4 -> 64B/point, contiguous in p
        *(vfloat4*)(mid + ((size_t)cg * N + p) * 16 + q * 4) = rv;
    }
}

// k5: both-sides-coalesced permutation. 64 dest points per block; round r = cg.
__global__ __launch_bounds__(256) void k5_permute(const float* __restrict__ mid,
                                                  const int* __restrict__ inv,
                                                  float* __restrict__ out, int N) {
    __shared__ float tile[64 * 132];    // 33,792 B (132-stride keeps 16B alignment)
    __shared__ int   sp[64];
    int n0 = blockIdx.x * 64;
    int t  = threadIdx.x;
    int cnt = min(64, N - n0);

    if (t < 64) sp[t] = (t < cnt) ? inv[n0 + t] : 0;
    __syncthreads();

    int j = t >> 2;                 // point 0..63
    int q = t & 3;                  // 16B chunk within 64B cg-chunk
    vfloat4 g[NCG];
#pragma unroll
    for (int r = 0; r < NCG; ++r) {
        if (j < cnt)
            g[r] = *(const vfloat4*)(mid + ((size_t)r * N + sp[j]) * 16 + q * 4);
    }
#pragma unroll
    for (int r = 0; r < NCG; ++r) {
        if (j < cnt)
            *(vfloat4*)&tile[j * 132 + r * 16 + q * 4] = g[r];
    }
    __syncthreads();

    // 32 rounds x 4 channels: lanes jj=0..63 write contiguous 256B per channel row.
    int jj = t & 63;
    for (int s = 0; s < 32; ++s) {
        int c = s * 4 + (t >> 6);
        if (jj < cnt)
            __builtin_nontemporal_store(tile[jj * 132 + c], out + (size_t)c * N + n0 + jj);
    }
}

// ---- Fallback (R2 structure, known-good) if ws too small ----
constexpr int F_CPG = 2;
constexpr int F_CG  = C / F_CPG;
constexpr int F_GPX = F_CG / 8;

__global__ __launch_bounds__(256) void fallback_kernel(
    const float* __restrict__ fmap, const float* __restrict__ uv,
    const int* __restrict__ dsp, float* __restrict__ out, int N, int NBX)
{
    int bid = blockIdx.x;
    int xcd = bid & 7;
    int jj  = bid >> 3;
    int g_local = jj / NBX;
    int nb      = jj - g_local * NBX;
    int g   = xcd * F_GPX + g_local;

    int n = nb * 256 + threadIdx.x;
    if (n >= N) return;

    float dsf = (float)dsp[0];
    float2 p = ((const float2*)uv)[n];
    float u = p.x / dsf, v = p.y / dsf;
    int u_lo = (int)u, v_lo = (int)v;
    float du = u - (float)u_lo, dv = v - (float)v_lo;

    float w00 = (1.0f - dv) * (1.0f - du);
    float w10 = dv * (1.0f - du);
    float w01 = (1.0f - dv) * du;
    float w11 = dv * du;

    int cbase = g * F_CPG;
    const float* fp = fmap + (size_t)cbase * HW + (size_t)v_lo * W + u_lo;
    float*       op = out  + (size_t)cbase * N + n;
#pragma unroll
    for (int c = 0; c < F_CPG; ++c) {
        float f00 = fp[0], f01 = fp[1], f10 = fp[W], f11 = fp[W + 1];
        float r = f00 * w00 + f10 * w10 + f01 * w01 + f11 * w11;
        __builtin_nontemporal_store(r, op);
        fp += HW; op += N;
    }
}

extern "C" void kernel_launch(void* const* d_in, const int* in_sizes, int n_in,
                              void* d_out, int out_size, void* d_ws, size_t ws_size,
                              hipStream_t stream)
{
    const float* fmap = (const float*)d_in[0];
    const float* uv   = (const float*)d_in[1];
    const int*   dsp  = (const int*)d_in[2];
    float*       out  = (float*)d_out;

    int N = in_sizes[1] / 2;

    // ws layout
    size_t off_hist   = 0;
    size_t off_cursor = 8192;      // NBINS=1197 ints = 4788 B
    size_t off_starts = 16384;     // NBINS+1 ints
    size_t off_inv    = 24576;
    size_t off_sorted = off_inv + (((size_t)N * 4 + 255) & ~(size_t)255);
    size_t off_mid    = off_sorted + (((size_t)N * 16 + 255) & ~(size_t)255);
    size_t need       = off_mid + (size_t)N * C * 4;

    if (ws_size < need) {
        int NBX = (N + 255) / 256;
        dim3 grid(NBX * F_CG);
        fallback_kernel<<<grid, dim3(256), 0, stream>>>(fmap, uv, dsp, out, N, NBX);
        return;
    }

    char* ws = (char*)d_ws;
    int*   hist   = (int*)(ws + off_hist);
    int*   cursor = (int*)(ws + off_cursor);
    int*   starts = (int*)(ws + off_starts);
    int*   inv    = (int*)(ws + off_inv);
    uint4* sorted = (uint4*)(ws + off_sorted);
    float* mid    = (float*)(ws + off_mid);

    int nb = (N + 255) / 256;
    k0_zero<<<1, 512, 0, stream>>>(hist, cursor);
    k1_count<<<nb, 256, 0, stream>>>(uv, dsp, hist, N);
    k2_scan<<<1, 1024, 0, stream>>>(hist, starts, cursor);
    k3_scatter<<<nb, 256, 0, stream>>>(uv, dsp, cursor, sorted, inv, N);
    k4_resample<<<NBINS * NCG, 256, 0, stream>>>(fmap, sorted, starts, mid, N);
    k5_permute<<<(N + 63) / 64, 256, 0, stream>>>(mid, inv, out, N);
}